// Round 5
// baseline (1711.577 us; speedup 1.0000x reference)
//
#include <hip/hip_runtime.h>

// ============================================================================
// Wired CfC (NCP) scan, B=256 x T=1024, 3 layers (hid 135/89/32) + final FC.
//
// Round 5: rounds 3/4 proved the backend will NOT budget >128 arch-VGPRs for
// this kernel (waves_per_eu(2,2) ignored for VGPRs; WRITE_SIZE=68MB scratch).
// So fit UNDER 128 instead: K split 4 ways across lane quads. 1024 threads,
// unit = tid>>2 (0..255), quarter = tid&3 owns 56 of KPAD=224. Per-thread
// weights 3 x 28 half2 = 84 VGPRs (+~30 misc ~= 115 < 128, no spill).
// 16 waves x 128 regs = the whole 512-reg/SIMD file; waves_per_eu(4,4) pins
// the allocator at the 128 budget it wants anyway. Quarter-combine via
// __shfl_xor(.,1) + __shfl_xor(.,2) (quads are adjacent lanes in-wave).
//
// Unchanged: persistent-RNN (1 batch row/block), masked W1/W2 + folded Wa+Wb
// pre-cast to f16 in VGPRs, v_dot2_f32_f16 inner loop, layers pipelined
// across timesteps (1 barrier/tick), ping-pong f16 xcat LDS, exp2/rcp
// activations, fp32 h for the FC epilogue.
// Cycle model: 4 waves/SIMD x 115 VALU x 2cyc ~= 920 cyc/tick -> ~392us
// floor; predict 430-550us.
// ============================================================================

typedef _Float16 half2v __attribute__((ext_vector_type(2)));
typedef _Float16 half8v __attribute__((ext_vector_type(8)));

#define NBLK   256
#define NTHR   1024
#define TSTEPS 1024
#define KPAD   224
#define KQ     56      // KPAD / 4 per lane
#define NKB    7       // KQ / 8 blocks per lane

struct Ptrs {
    const float* x;
    const unsigned int* msk[3];   // bool in reference -> int32 on device
    const float* W1[3];
    const float* W2[3];
    const float* Wa[3];
    const float* Wb[3];
    const float* b1[3];
    const float* b2[3];
    const float* ba[3];
    const float* bb[3];
    const float* fcW;
    const float* fcb;
};

__device__ __forceinline__ float fexp2(float x) {
#if __has_builtin(__builtin_amdgcn_exp2f)
    return __builtin_amdgcn_exp2f(x);
#else
    return exp2f(x);
#endif
}
__device__ __forceinline__ float frcp(float x) {
#if __has_builtin(__builtin_amdgcn_rcpf)
    return __builtin_amdgcn_rcpf(x);
#else
    return 1.0f / x;
#endif
}
// sigmoid(x) = 1/(1+2^(-x*log2e)); tanh(x) = 2/(1+2^(-2x*log2e)) - 1
__device__ __forceinline__ float fsig(float x) {
    return frcp(1.0f + fexp2(-1.442695041f * x));
}
__device__ __forceinline__ float ftanh(float x) {
    return 2.0f * frcp(1.0f + fexp2(-2.885390082f * x)) - 1.0f;
}

#if __has_builtin(__builtin_amdgcn_fdot2)
#define FD(a, b, c) __builtin_amdgcn_fdot2((a), (b), (c), false)
#else
__device__ __forceinline__ float fd_fallback(half2v a, half2v b, float c) {
    return c + (float)a[0] * (float)b[0] + (float)a[1] * (float)b[1];
}
#define FD(a, b, c) fd_fallback((a), (b), (c))
#endif

__global__ __launch_bounds__(NTHR)
__attribute__((amdgpu_waves_per_eu(4, 4)))
void cfc_kernel(Ptrs P, float* __restrict__ out) {
    // xc[parity][layer][k] : f16 concat inputs per layer, zero-padded to KPAD.
    __shared__ __align__(16) _Float16 xc[2][3][KPAD];
    __shared__ __align__(16) float hn[256];

    const int tid  = threadIdx.x;
    const int b    = blockIdx.x;
    const int unit = tid >> 2;   // output unit 0..255
    const int q    = tid & 3;    // which K-quarter this lane owns

    // ---- unit role ----
    int L, n;
    if (unit < 135)      { L = 0; n = unit; }
    else if (unit < 224) { L = 1; n = unit - 135; }
    else                 { L = 2; n = unit - 224; }
    const int K    = (L == 0) ? 199 : ((L == 1) ? 224 : 121);
    const int HOFF = (L == 0) ? 0   : ((L == 1) ? 135 : 224);

    // ---- zero LDS (padding regions must read as 0.0) ----
    {
        int* z = (int*)&xc[0][0][0];
        for (int i = tid; i < 2 * 3 * KPAD / 2; i += NTHR) z[i] = 0;
    }
    __syncthreads();

    // ---- x staging: threads 960..1023 own one of the 64 input features ----
    const int xlane = tid - 960;
    float xpend = 0.0f;
    if (xlane >= 0) {
        xc[0][0][xlane] = (_Float16)P.x[((size_t)b * TSTEPS + 0) * 64 + xlane];
        xpend           = P.x[((size_t)b * TSTEPS + 1) * 64 + xlane];
    }

    // ---- weight preload: this lane's K-quarter; fold mask, Wa+Wb; f16 ----
    const float* W1p        = P.W1[L];
    const float* W2p        = P.W2[L];
    const float* Wap        = P.Wa[L];
    const float* Wbp        = P.Wb[L];
    const unsigned int* mkp = P.msk[L];
    const int nK   = n * K;
    const int koff = q * KQ;

    half2v wr1[KQ / 2], wr2[KQ / 2], wra[KQ / 2];
#pragma unroll
    for (int i = 0; i < KQ / 2; ++i) {
        const int k0 = koff + 2 * i, k1 = koff + 2 * i + 1;
        float u0 = 0.f, u1 = 0.f, v0 = 0.f, v1 = 0.f, a0 = 0.f, a1 = 0.f;
        if (k0 < K) {
            const int idx = nK + k0;
            const float mm = (mkp[idx] != 0u) ? 1.0f : 0.0f;
            u0 = W1p[idx] * mm;
            v0 = W2p[idx] * mm;
            a0 = Wap[idx] + Wbp[idx];
        }
        if (k1 < K) {
            const int idx = nK + k1;
            const float mm = (mkp[idx] != 0u) ? 1.0f : 0.0f;
            u1 = W1p[idx] * mm;
            v1 = W2p[idx] * mm;
            a1 = Wap[idx] + Wbp[idx];
        }
        wr1[i] = half2v{(_Float16)u0, (_Float16)u1};
        wr2[i] = half2v{(_Float16)v0, (_Float16)v1};
        wra[i] = half2v{(_Float16)a0, (_Float16)a1};
    }
    const float bv1 = P.b1[L][n];
    const float bv2 = P.b2[L][n];
    const float bva = P.ba[L][n] + P.bb[L][n];
    __syncthreads();

    // ---- main scan: layer L computes timestep (tick - L); 1 barrier/tick ----
    for (int tick = 0; tick < TSTEPS + 2; ++tick) {
        // stage x(tick+1) (loaded 1 tick ago), prefetch x(tick+2)
        if (xlane >= 0) {
            if (tick + 1 < TSTEPS)
                xc[(tick + 1) & 1][0][xlane] = (_Float16)xpend;
            if (tick + 2 < TSTEPS)
                xpend = P.x[((size_t)b * TSTEPS + (tick + 2)) * 64 + xlane];
        }

        const int s = tick - L;
        if (s >= 0 && s < TSTEPS) {
            const _Float16* src = &xc[s & 1][L][koff];
            float ac0 = 0.f, ac1 = 0.f, ac2 = 0.f, ac3 = 0.f, ac4 = 0.f, ac5 = 0.f;
#pragma unroll
            for (int kb = 0; kb < NKB; ++kb) {
                const half8v xv = *(const half8v*)(src + kb * 8);
                const half2v x0 = {xv[0], xv[1]};
                const half2v x1 = {xv[2], xv[3]};
                const half2v x2 = {xv[4], xv[5]};
                const half2v x3 = {xv[6], xv[7]};
                const int k4 = kb * 4;
                ac0 = FD(x0, wr1[k4 + 0], ac0);
                ac2 = FD(x0, wr2[k4 + 0], ac2);
                ac4 = FD(x0, wra[k4 + 0], ac4);
                ac1 = FD(x1, wr1[k4 + 1], ac1);
                ac3 = FD(x1, wr2[k4 + 1], ac3);
                ac5 = FD(x1, wra[k4 + 1], ac5);
                ac0 = FD(x2, wr1[k4 + 2], ac0);
                ac2 = FD(x2, wr2[k4 + 2], ac2);
                ac4 = FD(x2, wra[k4 + 2], ac4);
                ac1 = FD(x3, wr1[k4 + 3], ac1);
                ac3 = FD(x3, wr2[k4 + 3], ac3);
                ac5 = FD(x3, wra[k4 + 3], ac5);
            }
            // combine the four K-quarters (quads are adjacent lanes in-wave)
            float s1 = ac0 + ac1;
            float s2 = ac2 + ac3;
            float sa = ac4 + ac5;
            s1 += __shfl_xor(s1, 1, 64);
            s2 += __shfl_xor(s2, 1, 64);
            sa += __shfl_xor(sa, 1, 64);
            s1 += __shfl_xor(s1, 2, 64);
            s2 += __shfl_xor(s2, 2, 64);
            sa += __shfl_xor(sa, 2, 64);
            // all four lanes now hold identical sums -> identical h
            const float f1 = ftanh(s1 + bv1);
            const float f2 = ftanh(s2 + bv2);
            const float tg = fsig(sa + bva);
            const float h  = f1 + tg * (f2 - f1);
            const _Float16 hv = (_Float16)h;

            const int pA = s & 1;        // consumer at timestep s (next layer)
            const int pB = (s + 1) & 1;  // consumer at timestep s+1 (own recurrence)
            // split the stores across the quad
            if (q == 0) {
                if (L == 0)      xc[pA][1][n] = hv;        // -> layer1 input part
                else if (L == 1) xc[pA][2][n] = hv;        // -> layer2 input part
                if (s == TSTEPS - 1) hn[HOFF + n] = h;     // fp32 final state
            } else if (q == 1) {
                if (L == 0)      xc[pB][0][64 + n]  = hv;  // own recurrence
                else if (L == 1) xc[pB][1][135 + n] = hv;
                else             xc[pB][2][89 + n]  = hv;
            }
        }
        __syncthreads();
    }

    // ---- FC epilogue: out[b][o] = dot(hn, fcW[o,:]) + fcb[o], K-quarter ----
    {
        const int o = unit;
        const float4* wr = (const float4*)(P.fcW + (size_t)o * 256 + q * 64);
        const float4* hr = (const float4*)(hn + q * 64);
        float acc = (q == 0) ? P.fcb[o] : 0.0f;
#pragma unroll
        for (int d = 0; d < 16; ++d) {
            const float4 a = hr[d];
            const float4 w = wr[d];
            acc += a.x * w.x + a.y * w.y + a.z * w.z + a.w * w.w;
        }
        acc += __shfl_xor(acc, 1, 64);
        acc += __shfl_xor(acc, 2, 64);
        if (q == 0) out[(size_t)b * 256 + o] = acc;
    }
}

extern "C" void kernel_launch(void* const* d_in, const int* in_sizes, int n_in,
                              void* d_out, int out_size, void* d_ws, size_t ws_size,
                              hipStream_t stream) {
    (void)in_sizes; (void)n_in; (void)out_size; (void)d_ws; (void)ws_size;
    Ptrs P;
    P.x = (const float*)d_in[0];
    for (int l = 0; l < 3; ++l) {
        const int base = 1 + l * 9;
        P.msk[l] = (const unsigned int*)d_in[base + 0];
        P.W1[l]  = (const float*)d_in[base + 1];
        P.W2[l]  = (const float*)d_in[base + 2];
        P.Wa[l]  = (const float*)d_in[base + 3];
        P.Wb[l]  = (const float*)d_in[base + 4];
        P.b1[l]  = (const float*)d_in[base + 5];
        P.b2[l]  = (const float*)d_in[base + 6];
        P.ba[l]  = (const float*)d_in[base + 7];
        P.bb[l]  = (const float*)d_in[base + 8];
    }
    P.fcW = (const float*)d_in[28];
    P.fcb = (const float*)d_in[29];

    hipLaunchKernelGGL(cfc_kernel, dim3(NBLK), dim3(NTHR), 0, stream,
                       P, (float*)d_out);
}

// Round 7
// 1642.874 us; speedup vs baseline: 1.0418x; 1.0418x over previous
//
#include <hip/hip_runtime.h>

// ============================================================================
// Wired CfC (NCP) scan, B=256 x T=1024, 3 layers (hid 135/89/32) + final FC.
//
// Round 7 = round 6 with the compile fix (macro args can't contain braced
// initializer lists -> bind half2v locals before FD()).
//
// Rounds 2/3/5 proved the backend pins block VGPR total to 65536 regs
// (NTHR x grant = const; 2 blocks/CU heuristic) and spills the rest to
// scratch/HBM (WRITE_SIZE ~70MB). Folded weights = 304 KB/block > 256 KB of
// granted registers -> overflow must live in LDS, not scratch.
//
// Hybrid: 512 threads, unit=tid>>1, half=tid&1 (112 f16 of K per lane).
//  - Registers: W1 (56 half2) + W2-head (40 half2) = 96 regs (+~25 misc <128).
//  - LDS: W2-tail (16 half2) + Wa (56 half2) = 288 B/thread, streamed each
//    tick as 18 ds_read_b128. Slice stride 304 B = 19 lines (odd) -> each
//    16-lane beat hits each bank-group exactly 2x = conflict-free (m136).
//  - LDS total = 4 KB (xc/hn) + 512*304 = 156 KB -> dynamic shared memory
//    (hipFuncSetAttribute, >64KB static limit), 1 block/CU.
// Unchanged: persistent-RNN (1 row/block), pair-combine via __shfl_xor(.,1),
// layer-pipelined scan (1 barrier/tick), ping-pong f16 xcat, exp2/rcp
// activations, fp32 h + FC epilogue.
// Model: VALU ~770 cyc/tick, DS ~800 cyc/tick overlapped -> predict 380-550us.
// ============================================================================

typedef _Float16 half2v __attribute__((ext_vector_type(2)));
typedef _Float16 half8v __attribute__((ext_vector_type(8)));

#define NBLK    256
#define NTHR    512
#define TSTEPS  1024
#define KPAD    224
#define KHALF   112
#define NKB     14        // KHALF / 8 x-chunks per lane
#define W2REG   10        // chunks 0..9 of W2 in regs, 10..13 in LDS
#define WSTRIDE 304       // per-thread LDS slice stride (19 x 16B, odd)
#define WOFF    4096      // weight pool offset in dynamic smem
#define SMEM_BYTES (WOFF + NTHR * WSTRIDE)   // 159744 <= 163840

struct Ptrs {
    const float* x;
    const unsigned int* msk[3];   // bool in reference -> int32 on device
    const float* W1[3];
    const float* W2[3];
    const float* Wa[3];
    const float* Wb[3];
    const float* b1[3];
    const float* b2[3];
    const float* ba[3];
    const float* bb[3];
    const float* fcW;
    const float* fcb;
};

__device__ __forceinline__ float fexp2(float x) {
#if __has_builtin(__builtin_amdgcn_exp2f)
    return __builtin_amdgcn_exp2f(x);
#else
    return exp2f(x);
#endif
}
__device__ __forceinline__ float frcp(float x) {
#if __has_builtin(__builtin_amdgcn_rcpf)
    return __builtin_amdgcn_rcpf(x);
#else
    return 1.0f / x;
#endif
}
__device__ __forceinline__ float fsig(float x) {
    return frcp(1.0f + fexp2(-1.442695041f * x));
}
__device__ __forceinline__ float ftanh(float x) {
    return 2.0f * frcp(1.0f + fexp2(-2.885390082f * x)) - 1.0f;
}

#if __has_builtin(__builtin_amdgcn_fdot2)
#define FD(a, b, c) __builtin_amdgcn_fdot2((a), (b), (c), false)
#else
__device__ __forceinline__ float fd_fallback(half2v a, half2v b, float c) {
    return c + (float)a[0] * (float)b[0] + (float)a[1] * (float)b[1];
}
#define FD(a, b, c) fd_fallback((a), (b), (c))
#endif

__global__ __launch_bounds__(NTHR)
__attribute__((amdgpu_waves_per_eu(2)))
void cfc_kernel(Ptrs P, float* __restrict__ out) {
    extern __shared__ __align__(16) char smem[];
    // layout: [0, 2688)  xc[2][3][KPAD] f16 ping-pong concat inputs
    //         [2688, 3712) hn[256] f32 final state
    //         [WOFF, ...) per-thread weight slices, WSTRIDE bytes each:
    //             bytes [0,64): W2 chunks 10..13 ; bytes [64,288): Wa 0..13
    _Float16 (*xc)[3][KPAD] = (_Float16 (*)[3][KPAD])smem;
    float* hn = (float*)(smem + 2688);

    const int tid  = threadIdx.x;
    const int b    = blockIdx.x;
    const int unit = tid >> 1;   // output unit 0..255
    const int half = tid & 1;    // which K-half this lane owns

    int L, n;
    if (unit < 135)      { L = 0; n = unit; }
    else if (unit < 224) { L = 1; n = unit - 135; }
    else                 { L = 2; n = unit - 224; }
    const int K    = (L == 0) ? 199 : ((L == 1) ? 224 : 121);
    const int HOFF = (L == 0) ? 0   : ((L == 1) ? 135 : 224);

    // ---- zero xc (padding must read 0.0) ----
    {
        int* z = (int*)smem;
        for (int i = tid; i < 2688 / 4; i += NTHR) z[i] = 0;
    }
    __syncthreads();

    // ---- x staging: threads 448..511 own one of the 64 input features ----
    const int xlane = tid - 448;
    float xpend = 0.0f;
    if (xlane >= 0) {
        xc[0][0][xlane] = (_Float16)P.x[((size_t)b * TSTEPS + 0) * 64 + xlane];
        xpend           = P.x[((size_t)b * TSTEPS + 1) * 64 + xlane];
    }

    // ---- weight preload ----
    const float* W1p        = P.W1[L];
    const float* W2p        = P.W2[L];
    const float* Wap        = P.Wa[L];
    const float* Wbp        = P.Wb[L];
    const unsigned int* mkp = P.msk[L];
    const int nK   = n * K;
    const int koff = half * KHALF;

    _Float16* wsl = (_Float16*)(smem + WOFF + tid * WSTRIDE);

    // registers: W1 full K-half, W2 chunks 0..W2REG-1
    half2v wr1[KHALF / 2], wr2[W2REG * 4];
#pragma unroll
    for (int i = 0; i < KHALF / 2; ++i) {
        const int k0 = koff + 2 * i, k1 = koff + 2 * i + 1;
        float u0 = 0.f, u1 = 0.f;
        if (k0 < K) { const int idx = nK + k0; u0 = mkp[idx] ? W1p[idx] : 0.f; }
        if (k1 < K) { const int idx = nK + k1; u1 = mkp[idx] ? W1p[idx] : 0.f; }
        wr1[i] = half2v{(_Float16)u0, (_Float16)u1};
    }
#pragma unroll
    for (int i = 0; i < W2REG * 4; ++i) {
        const int k0 = koff + 2 * i, k1 = koff + 2 * i + 1;
        float v0 = 0.f, v1 = 0.f;
        if (k0 < K) { const int idx = nK + k0; v0 = mkp[idx] ? W2p[idx] : 0.f; }
        if (k1 < K) { const int idx = nK + k1; v1 = mkp[idx] ? W2p[idx] : 0.f; }
        wr2[i] = half2v{(_Float16)v0, (_Float16)v1};
    }
    // LDS: W2 chunks W2REG..13
    for (int c = 0; c < NKB - W2REG; ++c) {
        half8v w;
#pragma unroll
        for (int j = 0; j < 8; ++j) {
            const int k = koff + (W2REG + c) * 8 + j;
            float v = 0.f;
            if (k < K) { const int idx = nK + k; v = mkp[idx] ? W2p[idx] : 0.f; }
            w[j] = (_Float16)v;
        }
        *((half8v*)(wsl + c * 8)) = w;
    }
    // LDS: Wa (=Wa+Wb) chunks 0..13
    for (int c = 0; c < NKB; ++c) {
        half8v w;
#pragma unroll
        for (int j = 0; j < 8; ++j) {
            const int k = koff + c * 8 + j;
            float v = 0.f;
            if (k < K) { const int idx = nK + k; v = Wap[idx] + Wbp[idx]; }
            w[j] = (_Float16)v;
        }
        *((half8v*)(wsl + 32 + c * 8)) = w;
    }
    const float bv1 = P.b1[L][n];
    const float bv2 = P.b2[L][n];
    const float bva = P.ba[L][n] + P.bb[L][n];
    __syncthreads();

    const _Float16* wa_l = wsl + 32;

    // ---- main scan: layer L computes timestep (tick - L); 1 barrier/tick ----
    for (int tick = 0; tick < TSTEPS + 2; ++tick) {
        if (xlane >= 0) {
            if (tick + 1 < TSTEPS)
                xc[(tick + 1) & 1][0][xlane] = (_Float16)xpend;
            if (tick + 2 < TSTEPS)
                xpend = P.x[((size_t)b * TSTEPS + (tick + 2)) * 64 + xlane];
        }

        const int s = tick - L;
        if (s >= 0 && s < TSTEPS) {
            const _Float16* src = &xc[s & 1][L][koff];
            float ac0 = 0.f, ac1 = 0.f, ac2 = 0.f, ac3 = 0.f, ac4 = 0.f, ac5 = 0.f;
#pragma unroll
            for (int kb = 0; kb < NKB; ++kb) {
                const half8v xv = *(const half8v*)(src + kb * 8);
                const half8v av = *(const half8v*)(wa_l + kb * 8);
                const half2v x0 = {xv[0], xv[1]};
                const half2v x1 = {xv[2], xv[3]};
                const half2v x2 = {xv[4], xv[5]};
                const half2v x3 = {xv[6], xv[7]};
                const half2v a0 = {av[0], av[1]};
                const half2v a1 = {av[2], av[3]};
                const half2v a2 = {av[4], av[5]};
                const half2v a3 = {av[6], av[7]};
                const int k4 = kb * 4;
                // W1 from regs
                ac0 = FD(x0, wr1[k4 + 0], ac0);
                ac1 = FD(x1, wr1[k4 + 1], ac1);
                ac0 = FD(x2, wr1[k4 + 2], ac0);
                ac1 = FD(x3, wr1[k4 + 3], ac1);
                // Wa from LDS
                ac4 = FD(x0, a0, ac4);
                ac5 = FD(x1, a1, ac5);
                ac4 = FD(x2, a2, ac4);
                ac5 = FD(x3, a3, ac5);
                // W2: head from regs, tail from LDS
                if (kb < W2REG) {
                    ac2 = FD(x0, wr2[k4 + 0], ac2);
                    ac3 = FD(x1, wr2[k4 + 1], ac3);
                    ac2 = FD(x2, wr2[k4 + 2], ac2);
                    ac3 = FD(x3, wr2[k4 + 3], ac3);
                } else {
                    const half8v wv = *(const half8v*)(wsl + (kb - W2REG) * 8);
                    const half2v w0 = {wv[0], wv[1]};
                    const half2v w1 = {wv[2], wv[3]};
                    const half2v w2 = {wv[4], wv[5]};
                    const half2v w3 = {wv[6], wv[7]};
                    ac2 = FD(x0, w0, ac2);
                    ac3 = FD(x1, w1, ac3);
                    ac2 = FD(x2, w2, ac2);
                    ac3 = FD(x3, w3, ac3);
                }
            }
            // combine the two K-halves (pairs are adjacent lanes in-wave)
            float s1 = ac0 + ac1;
            float s2 = ac2 + ac3;
            float sa = ac4 + ac5;
            s1 += __shfl_xor(s1, 1, 64);
            s2 += __shfl_xor(s2, 1, 64);
            sa += __shfl_xor(sa, 1, 64);
            const float f1 = ftanh(s1 + bv1);
            const float f2 = ftanh(s2 + bv2);
            const float tg = fsig(sa + bva);
            const float h  = f1 + tg * (f2 - f1);
            const _Float16 hv = (_Float16)h;

            const int pA = s & 1;        // consumer at timestep s (next layer)
            const int pB = (s + 1) & 1;  // consumer at timestep s+1 (own recurrence)
            if (half == 0) {
                if (L == 0)      xc[pA][1][n] = hv;        // -> layer1 input part
                else if (L == 1) xc[pA][2][n] = hv;        // -> layer2 input part
                if (s == TSTEPS - 1) hn[HOFF + n] = h;     // fp32 final state
            } else {
                if (L == 0)      xc[pB][0][64 + n]  = hv;  // own recurrence
                else if (L == 1) xc[pB][1][135 + n] = hv;
                else             xc[pB][2][89 + n]  = hv;
            }
        }
        __syncthreads();
    }

    // ---- FC epilogue: out[b][o] = dot(hn, fcW[o,:]) + fcb[o], K-split pair ----
    {
        const int o = unit;
        const float4* wr = (const float4*)(P.fcW + (size_t)o * 256 + half * 128);
        const float4* hr = (const float4*)(hn + half * 128);
        float acc = half ? 0.0f : P.fcb[o];
#pragma unroll 8
        for (int d = 0; d < 32; ++d) {
            const float4 a = hr[d];
            const float4 w = wr[d];
            acc += a.x * w.x + a.y * w.y + a.z * w.z + a.w * w.w;
        }
        acc += __shfl_xor(acc, 1, 64);
        if (half == 0) out[(size_t)b * 256 + o] = acc;
    }
}

extern "C" void kernel_launch(void* const* d_in, const int* in_sizes, int n_in,
                              void* d_out, int out_size, void* d_ws, size_t ws_size,
                              hipStream_t stream) {
    (void)in_sizes; (void)n_in; (void)out_size; (void)d_ws; (void)ws_size;
    Ptrs P;
    P.x = (const float*)d_in[0];
    for (int l = 0; l < 3; ++l) {
        const int base = 1 + l * 9;
        P.msk[l] = (const unsigned int*)d_in[base + 0];
        P.W1[l]  = (const float*)d_in[base + 1];
        P.W2[l]  = (const float*)d_in[base + 2];
        P.Wa[l]  = (const float*)d_in[base + 3];
        P.Wb[l]  = (const float*)d_in[base + 4];
        P.b1[l]  = (const float*)d_in[base + 5];
        P.b2[l]  = (const float*)d_in[base + 6];
        P.ba[l]  = (const float*)d_in[base + 7];
        P.bb[l]  = (const float*)d_in[base + 8];
    }
    P.fcW = (const float*)d_in[28];
    P.fcb = (const float*)d_in[29];

    // allow >64KB dynamic LDS (160 KiB/CU on gfx950); idempotent, capture-safe
    static bool attr_set = false;
    if (!attr_set) {
        (void)hipFuncSetAttribute((const void*)cfc_kernel,
                                  hipFuncAttributeMaxDynamicSharedMemorySize,
                                  SMEM_BYTES);
        attr_set = true;
    }

    hipLaunchKernelGGL(cfc_kernel, dim3(NBLK), dim3(NTHR), SMEM_BYTES, stream,
                       P, (float*)d_out);
}